// Round 1
// baseline (275.831 us; speedup 1.0000x reference)
//
#include <hip/hip_runtime.h>
#include <hip/hip_bf16.h>

// Fused self-attention block: LN -> QKV -> MHA(16 heads, dh=64) -> WO -> +x
// B=4, S=1024, HIDDEN=1024. All inputs fp32; big GEMMs run bf16 MFMA w/ fp32 accum.
//
// Workspace layout (48 MiB total):
//   [ 0,  8M)  normed   bf16 [4096][1024]
//   [ 8, 16M)  wcat     bf16 [wq;wk;wv;wo] = [4096][1024]
//   [16, 24M)  Qg       bf16 [B,H,S,64]
//   [24, 32M)  Kg       bf16 [B,H,S,64]
//   [32, 40M)  Vt       bf16 [B,H,64,S]
//   [40, 48M)  ctx      bf16 [4096][1024]  ([B,S,H,dh] flattened)

typedef unsigned short u16;
typedef __attribute__((ext_vector_type(8))) short short8;
typedef __attribute__((ext_vector_type(4))) float f32x4;

__device__ __forceinline__ u16 f2bf(float f) {
  union { float f; unsigned u; } cv; cv.f = f;
  unsigned u = cv.u + 0x7fffu + ((cv.u >> 16) & 1u);   // RNE
  return (u16)(u >> 16);
}

__device__ __forceinline__ void gload_lds16(const void* g, void* l) {
  __builtin_amdgcn_global_load_lds(
      (const __attribute__((address_space(1))) void*)g,
      (__attribute__((address_space(3))) void*)l, 16, 0, 0);
}

__device__ __forceinline__ f32x4 mfma16(short8 a, short8 b, f32x4 c) {
  return __builtin_amdgcn_mfma_f32_16x16x32_bf16(a, b, c, 0, 0, 0);
}

// ---------------- LayerNorm: fp32 in -> bf16 normed ----------------
__global__ __launch_bounds__(256) void ln_kernel(const float* __restrict__ x,
                                                 const float* __restrict__ gamma,
                                                 const float* __restrict__ beta,
                                                 u16* __restrict__ outn) {
  __shared__ float sm[4];
  const int row = blockIdx.x, t = threadIdx.x;
  float4 v = ((const float4*)(x + (size_t)row * 1024))[t];
  float s = v.x + v.y + v.z + v.w;
#pragma unroll
  for (int off = 32; off; off >>= 1) s += __shfl_down(s, off);
  if ((t & 63) == 0) sm[t >> 6] = s;
  __syncthreads();
  const float mu = (sm[0] + sm[1] + sm[2] + sm[3]) * (1.0f / 1024.0f);
  const float dx = v.x - mu, dy = v.y - mu, dz = v.z - mu, dw = v.w - mu;
  float vs = dx * dx + dy * dy + dz * dz + dw * dw;
  __syncthreads();
#pragma unroll
  for (int off = 32; off; off >>= 1) vs += __shfl_down(vs, off);
  if ((t & 63) == 0) sm[t >> 6] = vs;
  __syncthreads();
  const float var = (sm[0] + sm[1] + sm[2] + sm[3]) * (1.0f / 1024.0f);
  const float rstd = rsqrtf(var + 1e-5f);
  float4 g = ((const float4*)gamma)[t];
  float4 b = ((const float4*)beta)[t];
  uint2 pk;
  pk.x = (unsigned)f2bf(dx * rstd * g.x + b.x) | ((unsigned)f2bf(dy * rstd * g.y + b.y) << 16);
  pk.y = (unsigned)f2bf(dz * rstd * g.z + b.z) | ((unsigned)f2bf(dw * rstd * g.w + b.w) << 16);
  *(uint2*)&outn[(size_t)row * 1024 + t * 4] = pk;
}

// ---------------- weight convert fp32 -> bf16, concat [wq;wk;wv;wo] ----------------
__global__ __launch_bounds__(256) void cvt_w(const float* __restrict__ wq,
                                             const float* __restrict__ wk,
                                             const float* __restrict__ wv,
                                             const float* __restrict__ wo,
                                             u16* __restrict__ out) {
  const int i = blockIdx.x * 256 + threadIdx.x;  // 1M threads, 4 elems each
  const int e = i * 4;
  const int seg = e >> 20;
  const int off = e & 1048575;
  const float* src = (seg == 0) ? wq : (seg == 1) ? wk : (seg == 2) ? wv : wo;
  float4 v = *(const float4*)(src + off);
  uint2 pk;
  pk.x = (unsigned)f2bf(v.x) | ((unsigned)f2bf(v.y) << 16);
  pk.y = (unsigned)f2bf(v.z) | ((unsigned)f2bf(v.w) << 16);
  *(uint2*)&out[e] = pk;
}

// ---------------- bt-GEMM: C[M,N] = A[M,K] * Bt[N,K]^T  (K=1024) ----------------
// MODE 0: N=3072, scatter to Qg/Kg ([B,H,S,64]) and Vt ([B,H,64,S]) as bf16
// MODE 1: N=1024, fp32 out + residual
template <int MODE>
__global__ __launch_bounds__(256) void gemm_bt(const u16* __restrict__ A,
                                               const u16* __restrict__ Bm,
                                               u16* __restrict__ outQ, u16* __restrict__ outK,
                                               u16* __restrict__ outVt,
                                               float* __restrict__ outF,
                                               const float* __restrict__ resid) {
  constexpr int BK = 64, KK = 1024;
  __shared__ u16 As[128 * BK];
  __shared__ u16 Bs[128 * BK];
  const int m0 = blockIdx.y * 128, n0 = blockIdx.x * 128;
  const int t = threadIdx.x;
  const int wid = t >> 6, lane = t & 63;
  const int wm = (wid >> 1) * 64, wn = (wid & 1) * 64;
  const int lr = lane & 15, lg = lane >> 4;
  f32x4 acc[4][4] = {};
  const u16* aSrc = A + (size_t)(m0 + (t >> 3)) * KK + (t & 7) * 8;
  const u16* bSrc = Bm + (size_t)(n0 + (t >> 3)) * KK + (t & 7) * 8;

  for (int k0 = 0; k0 < KK; k0 += BK) {
    __syncthreads();
#pragma unroll
    for (int c = 0; c < 4; c++) {
      gload_lds16(aSrc + (size_t)c * 32 * KK + k0, As + c * 2048 + t * 8);
      gload_lds16(bSrc + (size_t)c * 32 * KK + k0, Bs + c * 2048 + t * 8);
    }
    __syncthreads();
    short8 af[4][2], bfr[4][2];
#pragma unroll
    for (int mi = 0; mi < 4; mi++)
#pragma unroll
      for (int kc = 0; kc < 2; kc++)
        af[mi][kc] = *(const short8*)&As[(wm + mi * 16 + lr) * BK + kc * 32 + lg * 8];
#pragma unroll
    for (int ni = 0; ni < 4; ni++)
#pragma unroll
      for (int kc = 0; kc < 2; kc++)
        bfr[ni][kc] = *(const short8*)&Bs[(wn + ni * 16 + lr) * BK + kc * 32 + lg * 8];
#pragma unroll
    for (int mi = 0; mi < 4; mi++)
#pragma unroll
      for (int ni = 0; ni < 4; ni++)
#pragma unroll
        for (int kc = 0; kc < 2; kc++)
          acc[mi][ni] = mfma16(af[mi][kc], bfr[ni][kc], acc[mi][ni]);
  }

#pragma unroll
  for (int mi = 0; mi < 4; mi++)
#pragma unroll
    for (int ni = 0; ni < 4; ni++)
#pragma unroll
      for (int r = 0; r < 4; r++) {
        const int i = m0 + wm + mi * 16 + lg * 4 + r;  // C row = (lane>>4)*4+reg
        const int j = n0 + wn + ni * 16 + lr;          // C col = lane&15
        const float val = acc[mi][ni][r];
        if (MODE == 0) {
          const int seg = j >> 10, jj = j & 1023;
          const int h = jj >> 6, d = jj & 63;
          const int b = i >> 10, s_ = i & 1023;
          const u16 bv = f2bf(val);
          if (seg == 0)      outQ[((size_t)(b * 16 + h) * 1024 + s_) * 64 + d] = bv;
          else if (seg == 1) outK[((size_t)(b * 16 + h) * 1024 + s_) * 64 + d] = bv;
          else               outVt[((size_t)(b * 16 + h) * 64 + d) * 1024 + s_] = bv;
        } else {
          const size_t o = (size_t)i * 1024 + j;
          outF[o] = val + resid[o];
        }
      }
}

// ---------------- flash attention: per (b,h,qtile=64) block, 4 waves x 16 q-rows ----------------
__global__ __launch_bounds__(256) void flash_kernel(const u16* __restrict__ Qg,
                                                    const u16* __restrict__ Kg,
                                                    const u16* __restrict__ Vt,
                                                    const float* __restrict__ mask,
                                                    u16* __restrict__ ctx) {
  const int h = blockIdx.x, qt = blockIdx.y, b = blockIdx.z;
  const int bh = b * 16 + h;
  __shared__ u16 Ks[64 * 64];       // [key][d]
  __shared__ u16 Vs[64 * 64];       // [d][key]   (from Vt)
  __shared__ u16 Ps[4][16 * 80];    // per-wave P [16 q][64 key], pad to 80 to break conflicts
  const int t = threadIdx.x, wid = t >> 6, lane = t & 63;
  const int lr = lane & 15, lg = lane >> 4;
  const int qbase = qt * 64 + wid * 16;

  // Q A-fragments in registers (rows qbase..+15, dh=64 -> 2 frags)
  short8 qf[2];
  {
    const u16* qrow = Qg + ((size_t)bh * 1024 + qbase + lr) * 64;
    qf[0] = *(const short8*)(qrow + lg * 8);
    qf[1] = *(const short8*)(qrow + 32 + lg * 8);
  }
  f32x4 octx[4] = {};
  float m_r[4], l_r[4];
#pragma unroll
  for (int r = 0; r < 4; r++) { m_r[r] = -1e30f; l_r[r] = 0.0f; }

  const u16* kS0 = Kg + (size_t)bh * 1024 * 64;
  const u16* vS0 = Vt + (size_t)bh * 64 * 1024;

  for (int kt = 0; kt < 16; kt++) {
    __syncthreads();
#pragma unroll
    for (int c = 0; c < 2; c++) {
      gload_lds16(kS0 + (size_t)(kt * 64 + c * 32 + (t >> 3)) * 64 + (t & 7) * 8,
                  Ks + c * 2048 + t * 8);
      gload_lds16(vS0 + (size_t)(c * 32 + (t >> 3)) * 1024 + kt * 64 + (t & 7) * 8,
                  Vs + c * 2048 + t * 8);
    }
    __syncthreads();

    // S = Q K^T * scale + maskbias; C rows = q (lg*4+r), cols = key (lr)
    float sv[4][4];  // [kn][r]
#pragma unroll
    for (int kn = 0; kn < 4; kn++) {
      short8 kf0 = *(const short8*)&Ks[(kn * 16 + lr) * 64 + lg * 8];
      short8 kf1 = *(const short8*)&Ks[(kn * 16 + lr) * 64 + 32 + lg * 8];
      f32x4 s = {};
      s = mfma16(qf[0], kf0, s);
      s = mfma16(qf[1], kf1, s);
#pragma unroll
      for (int r = 0; r < 4; r++) {
        const int qr = qbase + lg * 4 + r;
        const int kc = kt * 64 + kn * 16 + lr;
        const float mv = mask[((size_t)b * 1024 + qr) * 1024 + kc];
        sv[kn][r] = s[r] * 0.125f - 10000.0f * (1.0f - mv);
      }
    }

    // online softmax, rows live across 16 lanes of each quarter-wave
    float f_r[4];
#pragma unroll
    for (int r = 0; r < 4; r++) {
      float mt = fmaxf(fmaxf(sv[0][r], sv[1][r]), fmaxf(sv[2][r], sv[3][r]));
#pragma unroll
      for (int off = 1; off < 16; off <<= 1) mt = fmaxf(mt, __shfl_xor(mt, off));
      const float mn = fmaxf(m_r[r], mt);
      f_r[r] = __expf(m_r[r] - mn);
      m_r[r] = mn;
      float ps = 0.0f;
#pragma unroll
      for (int kn = 0; kn < 4; kn++) {
        const float p = __expf(sv[kn][r] - mn);
        sv[kn][r] = p;
        ps += p;
      }
#pragma unroll
      for (int off = 1; off < 16; off <<= 1) ps += __shfl_xor(ps, off);
      l_r[r] = l_r[r] * f_r[r] + ps;
    }
#pragma unroll
    for (int g = 0; g < 4; g++)
#pragma unroll
      for (int r = 0; r < 4; r++) octx[g][r] *= f_r[r];

    // P (C-layout) -> LDS -> A-frags for PV
#pragma unroll
    for (int kn = 0; kn < 4; kn++)
#pragma unroll
      for (int r = 0; r < 4; r++)
        Ps[wid][(lg * 4 + r) * 80 + kn * 16 + lr] = f2bf(sv[kn][r]);

    short8 pa0 = *(const short8*)&Ps[wid][lr * 80 + lg * 8];
    short8 pa1 = *(const short8*)&Ps[wid][lr * 80 + 32 + lg * 8];
#pragma unroll
    for (int g = 0; g < 4; g++) {
      short8 vf0 = *(const short8*)&Vs[(g * 16 + lr) * 64 + lg * 8];
      short8 vf1 = *(const short8*)&Vs[(g * 16 + lr) * 64 + 32 + lg * 8];
      octx[g] = mfma16(pa0, vf0, octx[g]);
      octx[g] = mfma16(pa1, vf1, octx[g]);
    }
  }

  // finalize: divide by l, write ctx as [B,S,H*dh] bf16
#pragma unroll
  for (int g = 0; g < 4; g++)
#pragma unroll
    for (int r = 0; r < 4; r++) {
      const int qr = qbase + lg * 4 + r;
      const float val = octx[g][r] / l_r[r];
      ctx[((size_t)b * 1024 + qr) * 1024 + h * 64 + g * 16 + lr] = f2bf(val);
    }
}

extern "C" void kernel_launch(void* const* d_in, const int* in_sizes, int n_in,
                              void* d_out, int out_size, void* d_ws, size_t ws_size,
                              hipStream_t stream) {
  const float* x     = (const float*)d_in[0];
  const float* mask  = (const float*)d_in[2];
  const float* wq    = (const float*)d_in[3];
  const float* wk    = (const float*)d_in[4];
  const float* wv    = (const float*)d_in[5];
  const float* wo    = (const float*)d_in[6];
  const float* gamma = (const float*)d_in[7];
  const float* beta  = (const float*)d_in[8];
  float* out = (float*)d_out;

  char* ws = (char*)d_ws;
  u16* normed = (u16*)(ws);                       // 8 MiB
  u16* wcat   = (u16*)(ws + (8ull << 20));        // 8 MiB ([wq;wk;wv;wo])
  u16* Qg     = (u16*)(ws + (16ull << 20));       // 8 MiB
  u16* Kg     = (u16*)(ws + (24ull << 20));       // 8 MiB
  u16* Vtg    = (u16*)(ws + (32ull << 20));       // 8 MiB
  u16* ctx    = (u16*)(ws + (40ull << 20));       // 8 MiB
  u16* wo_bf  = wcat + 3072ull * 1024;

  ln_kernel<<<4096, 256, 0, stream>>>(x, gamma, beta, normed);
  cvt_w<<<4096, 256, 0, stream>>>(wq, wk, wv, wo, wcat);
  // QKV: M=4096, N=3072
  gemm_bt<0><<<dim3(24, 32), 256, 0, stream>>>(normed, wcat, Qg, Kg, Vtg, nullptr, nullptr);
  // attention: grid x=h (16 heads share per-b mask slice in L2), y=qtile, z=b
  flash_kernel<<<dim3(16, 16, 4), 256, 0, stream>>>(Qg, Kg, Vtg, mask, ctx);
  // WO + residual: M=4096, N=1024
  gemm_bt<1><<<dim3(8, 32), 256, 0, stream>>>(ctx, wo_bf, nullptr, nullptr, nullptr, out, x);
}

// Round 2
// 270.068 us; speedup vs baseline: 1.0213x; 1.0213x over previous
//
#include <hip/hip_runtime.h>
#include <hip/hip_bf16.h>

// Fused self-attention block: LN -> QKV -> MHA(16 heads, dh=64) -> WO -> +x
// B=4, S=1024, HIDDEN=1024. All inputs fp32; big GEMMs run bf16 MFMA w/ fp32 accum.
//
// R2 changes vs R1:
//  - flash: XOR-swizzled K/V LDS tiles (pre-swizzled global_load_lds SOURCE, linear
//    dest, swizzled ds_read) to kill the 16-way bank conflict on 128B-stride rows.
//  - flash: swizzled P tile (was pad-80, still conflicted), hoisted mask row
//    pointers (imm-offset loads), Q pre-scaled by 0.125 (exact in bf16).
//
// Workspace layout (48 MiB total):
//   [ 0,  8M)  normed   bf16 [4096][1024]
//   [ 8, 16M)  wcat     bf16 [wq;wk;wv;wo] = [4096][1024]
//   [16, 24M)  Qg       bf16 [B,H,S,64]  (pre-scaled by 1/sqrt(64))
//   [24, 32M)  Kg       bf16 [B,H,S,64]
//   [32, 40M)  Vt       bf16 [B,H,64,S]
//   [40, 48M)  ctx      bf16 [4096][1024]  ([B,S,H,dh] flattened)

typedef unsigned short u16;
typedef __attribute__((ext_vector_type(8))) short short8;
typedef __attribute__((ext_vector_type(4))) float f32x4;

__device__ __forceinline__ u16 f2bf(float f) {
  union { float f; unsigned u; } cv; cv.f = f;
  unsigned u = cv.u + 0x7fffu + ((cv.u >> 16) & 1u);   // RNE
  return (u16)(u >> 16);
}

__device__ __forceinline__ void gload_lds16(const void* g, void* l) {
  __builtin_amdgcn_global_load_lds(
      (const __attribute__((address_space(1))) void*)g,
      (__attribute__((address_space(3))) void*)l, 16, 0, 0);
}

__device__ __forceinline__ f32x4 mfma16(short8 a, short8 b, f32x4 c) {
  return __builtin_amdgcn_mfma_f32_16x16x32_bf16(a, b, c, 0, 0, 0);
}

// ---------------- LayerNorm: fp32 in -> bf16 normed ----------------
__global__ __launch_bounds__(256) void ln_kernel(const float* __restrict__ x,
                                                 const float* __restrict__ gamma,
                                                 const float* __restrict__ beta,
                                                 u16* __restrict__ outn) {
  __shared__ float sm[4];
  const int row = blockIdx.x, t = threadIdx.x;
  float4 v = ((const float4*)(x + (size_t)row * 1024))[t];
  float s = v.x + v.y + v.z + v.w;
#pragma unroll
  for (int off = 32; off; off >>= 1) s += __shfl_down(s, off);
  if ((t & 63) == 0) sm[t >> 6] = s;
  __syncthreads();
  const float mu = (sm[0] + sm[1] + sm[2] + sm[3]) * (1.0f / 1024.0f);
  const float dx = v.x - mu, dy = v.y - mu, dz = v.z - mu, dw = v.w - mu;
  float vs = dx * dx + dy * dy + dz * dz + dw * dw;
  __syncthreads();
#pragma unroll
  for (int off = 32; off; off >>= 1) vs += __shfl_down(vs, off);
  if ((t & 63) == 0) sm[t >> 6] = vs;
  __syncthreads();
  const float var = (sm[0] + sm[1] + sm[2] + sm[3]) * (1.0f / 1024.0f);
  const float rstd = rsqrtf(var + 1e-5f);
  float4 g = ((const float4*)gamma)[t];
  float4 b = ((const float4*)beta)[t];
  uint2 pk;
  pk.x = (unsigned)f2bf(dx * rstd * g.x + b.x) | ((unsigned)f2bf(dy * rstd * g.y + b.y) << 16);
  pk.y = (unsigned)f2bf(dz * rstd * g.z + b.z) | ((unsigned)f2bf(dw * rstd * g.w + b.w) << 16);
  *(uint2*)&outn[(size_t)row * 1024 + t * 4] = pk;
}

// ---------------- weight convert fp32 -> bf16, concat [wq;wk;wv;wo] ----------------
__global__ __launch_bounds__(256) void cvt_w(const float* __restrict__ wq,
                                             const float* __restrict__ wk,
                                             const float* __restrict__ wv,
                                             const float* __restrict__ wo,
                                             u16* __restrict__ out) {
  const int i = blockIdx.x * 256 + threadIdx.x;  // 1M threads, 4 elems each
  const int e = i * 4;
  const int seg = e >> 20;
  const int off = e & 1048575;
  const float* src = (seg == 0) ? wq : (seg == 1) ? wk : (seg == 2) ? wv : wo;
  float4 v = *(const float4*)(src + off);
  uint2 pk;
  pk.x = (unsigned)f2bf(v.x) | ((unsigned)f2bf(v.y) << 16);
  pk.y = (unsigned)f2bf(v.z) | ((unsigned)f2bf(v.w) << 16);
  *(uint2*)&out[e] = pk;
}

// ---------------- bt-GEMM: C[M,N] = A[M,K] * Bt[N,K]^T  (K=1024) ----------------
// MODE 0: N=3072, scatter to Qg(*0.125)/Kg ([B,H,S,64]) and Vt ([B,H,64,S]) as bf16
// MODE 1: N=1024, fp32 out + residual
template <int MODE>
__global__ __launch_bounds__(256) void gemm_bt(const u16* __restrict__ A,
                                               const u16* __restrict__ Bm,
                                               u16* __restrict__ outQ, u16* __restrict__ outK,
                                               u16* __restrict__ outVt,
                                               float* __restrict__ outF,
                                               const float* __restrict__ resid) {
  constexpr int BK = 64, KK = 1024;
  __shared__ u16 As[128 * BK];
  __shared__ u16 Bs[128 * BK];
  const int m0 = blockIdx.y * 128, n0 = blockIdx.x * 128;
  const int t = threadIdx.x;
  const int wid = t >> 6, lane = t & 63;
  const int wm = (wid >> 1) * 64, wn = (wid & 1) * 64;
  const int lr = lane & 15, lg = lane >> 4;
  f32x4 acc[4][4] = {};
  const u16* aSrc = A + (size_t)(m0 + (t >> 3)) * KK + (t & 7) * 8;
  const u16* bSrc = Bm + (size_t)(n0 + (t >> 3)) * KK + (t & 7) * 8;

  for (int k0 = 0; k0 < KK; k0 += BK) {
    __syncthreads();
#pragma unroll
    for (int c = 0; c < 4; c++) {
      gload_lds16(aSrc + (size_t)c * 32 * KK + k0, As + c * 2048 + t * 8);
      gload_lds16(bSrc + (size_t)c * 32 * KK + k0, Bs + c * 2048 + t * 8);
    }
    __syncthreads();
    short8 af[4][2], bfr[4][2];
#pragma unroll
    for (int mi = 0; mi < 4; mi++)
#pragma unroll
      for (int kc = 0; kc < 2; kc++)
        af[mi][kc] = *(const short8*)&As[(wm + mi * 16 + lr) * BK + kc * 32 + lg * 8];
#pragma unroll
    for (int ni = 0; ni < 4; ni++)
#pragma unroll
      for (int kc = 0; kc < 2; kc++)
        bfr[ni][kc] = *(const short8*)&Bs[(wn + ni * 16 + lr) * BK + kc * 32 + lg * 8];
#pragma unroll
    for (int mi = 0; mi < 4; mi++)
#pragma unroll
      for (int ni = 0; ni < 4; ni++)
#pragma unroll
        for (int kc = 0; kc < 2; kc++)
          acc[mi][ni] = mfma16(af[mi][kc], bfr[ni][kc], acc[mi][ni]);
  }

#pragma unroll
  for (int mi = 0; mi < 4; mi++)
#pragma unroll
    for (int ni = 0; ni < 4; ni++)
#pragma unroll
      for (int r = 0; r < 4; r++) {
        const int i = m0 + wm + mi * 16 + lg * 4 + r;  // C row = (lane>>4)*4+reg
        const int j = n0 + wn + ni * 16 + lr;          // C col = lane&15
        const float val = acc[mi][ni][r];
        if (MODE == 0) {
          const int seg = j >> 10, jj = j & 1023;
          const int h = jj >> 6, d = jj & 63;
          const int b = i >> 10, s_ = i & 1023;
          if (seg == 0)      outQ[((size_t)(b * 16 + h) * 1024 + s_) * 64 + d] = f2bf(val * 0.125f);
          else if (seg == 1) outK[((size_t)(b * 16 + h) * 1024 + s_) * 64 + d] = f2bf(val);
          else               outVt[((size_t)(b * 16 + h) * 64 + d) * 1024 + s_] = f2bf(val);
        } else {
          const size_t o = (size_t)i * 1024 + j;
          outF[o] = val + resid[o];
        }
      }
}

// ---------------- flash attention: per (b,h,qtile=64) block, 4 waves x 16 q-rows ----------------
// K/V/P LDS tiles are chunk-XOR swizzled: element-chunk (row, cc) lives at
// lds[row*64 + (cc ^ (row&7))*8]. Staging keeps the LDS dest LINEAR and
// pre-swizzles the GLOBAL source chunk (rule: gload_lds writes base+lane*16).
__global__ __launch_bounds__(256) void flash_kernel(const u16* __restrict__ Qg,
                                                    const u16* __restrict__ Kg,
                                                    const u16* __restrict__ Vt,
                                                    const float* __restrict__ mask,
                                                    u16* __restrict__ ctx) {
  const int h = blockIdx.x, qt = blockIdx.y, b = blockIdx.z;
  const int bh = b * 16 + h;
  __shared__ u16 Ks[64 * 64];       // swizzled [key][d]
  __shared__ u16 Vs[64 * 64];       // swizzled [d][key]  (from Vt)
  __shared__ u16 Ps[4][16 * 64];    // per-wave swizzled P [16 q][64 key]
  const int t = threadIdx.x, wid = t >> 6, lane = t & 63;
  const int lr = lane & 15, lg = lane >> 4;
  const int hR = lr & 7;            // row&7 for fragment rows (16-aligned blocks)
  const int qbase = qt * 64 + wid * 16;

  // Q A-fragments in registers (rows qbase..+15, dh=64 -> 2 frags); Q pre-scaled
  short8 qf[2];
  {
    const u16* qrow = Qg + ((size_t)bh * 1024 + qbase + lr) * 64;
    qf[0] = *(const short8*)(qrow + lg * 8);
    qf[1] = *(const short8*)(qrow + 32 + lg * 8);
  }
  f32x4 octx[4] = {};
  float m_r[4], l_r[4];
#pragma unroll
  for (int r = 0; r < 4; r++) { m_r[r] = -1e30f; l_r[r] = 0.0f; }

  const u16* kS0 = Kg + (size_t)bh * 65536;
  const u16* vS0 = Vt + (size_t)bh * 65536;
  const int srow = t >> 3;          // 0..31 staging row within c-half
  const int scb = t & 7;            // staging chunk

  // hoisted mask row pointers (advance by 64 floats per k-tile)
  const float* mrow[4];
#pragma unroll
  for (int r = 0; r < 4; r++)
    mrow[r] = mask + ((size_t)b * 1024 + qbase + lg * 4 + r) * 1024 + lr;

  for (int kt = 0; kt < 16; kt++) {
    __syncthreads();
#pragma unroll
    for (int c = 0; c < 2; c++) {
      const int row = c * 32 + srow;
      const int sc = (scb ^ (row & 7)) * 8;   // pre-swizzled source chunk
      gload_lds16(kS0 + (size_t)(kt * 64 + row) * 64 + sc, Ks + c * 2048 + t * 8);
      gload_lds16(vS0 + (size_t)row * 1024 + kt * 64 + sc, Vs + c * 2048 + t * 8);
    }
    __syncthreads();

    // S = Q K^T (+mask bias); C rows = q (lg*4+r), cols = key (lr)
    float sv[4][4];  // [kn][r]
#pragma unroll
    for (int kn = 0; kn < 4; kn++) {
      const int R = kn * 16 + lr;
      short8 kf0 = *(const short8*)&Ks[R * 64 + ((lg ^ hR) << 3)];
      short8 kf1 = *(const short8*)&Ks[R * 64 + (((lg + 4) ^ hR) << 3)];
      f32x4 s = {};
      s = mfma16(qf[0], kf0, s);
      s = mfma16(qf[1], kf1, s);
#pragma unroll
      for (int r = 0; r < 4; r++) {
        const float mv = mrow[r][kn * 16];
        sv[kn][r] = fmaf(10000.0f, mv, s[r]) - 10000.0f;
      }
    }

    // online softmax, rows live across 16 lanes of each quarter-wave
    float f_r[4];
#pragma unroll
    for (int r = 0; r < 4; r++) {
      float mt = fmaxf(fmaxf(sv[0][r], sv[1][r]), fmaxf(sv[2][r], sv[3][r]));
#pragma unroll
      for (int off = 1; off < 16; off <<= 1) mt = fmaxf(mt, __shfl_xor(mt, off));
      const float mn = fmaxf(m_r[r], mt);
      f_r[r] = __expf(m_r[r] - mn);
      m_r[r] = mn;
      float ps = 0.0f;
#pragma unroll
      for (int kn = 0; kn < 4; kn++) {
        const float p = __expf(sv[kn][r] - mn);
        sv[kn][r] = p;
        ps += p;
      }
#pragma unroll
      for (int off = 1; off < 16; off <<= 1) ps += __shfl_xor(ps, off);
      l_r[r] = l_r[r] * f_r[r] + ps;
    }
#pragma unroll
    for (int g = 0; g < 4; g++)
#pragma unroll
      for (int r = 0; r < 4; r++) octx[g][r] *= f_r[r];

    // P (C-layout) -> swizzled LDS -> A-frags for PV
#pragma unroll
    for (int kn = 0; kn < 4; kn++)
#pragma unroll
      for (int r = 0; r < 4; r++) {
        const int row = lg * 4 + r;
        const int kc = kn * 16 + lr;
        Ps[wid][row * 64 + (((kc >> 3) ^ (row & 7)) << 3) + (kc & 7)] = f2bf(sv[kn][r]);
      }

    short8 pa0 = *(const short8*)&Ps[wid][lr * 64 + ((lg ^ hR) << 3)];
    short8 pa1 = *(const short8*)&Ps[wid][lr * 64 + (((lg + 4) ^ hR) << 3)];
#pragma unroll
    for (int g = 0; g < 4; g++) {
      const int R = g * 16 + lr;
      short8 vf0 = *(const short8*)&Vs[R * 64 + ((lg ^ hR) << 3)];
      short8 vf1 = *(const short8*)&Vs[R * 64 + (((lg + 4) ^ hR) << 3)];
      octx[g] = mfma16(pa0, vf0, octx[g]);
      octx[g] = mfma16(pa1, vf1, octx[g]);
    }
#pragma unroll
    for (int r = 0; r < 4; r++) mrow[r] += 64;
  }

  // finalize: divide by l, write ctx as [B,S,H*dh] bf16
#pragma unroll
  for (int g = 0; g < 4; g++)
#pragma unroll
    for (int r = 0; r < 4; r++) {
      const int qr = qbase + lg * 4 + r;
      const float val = octx[g][r] / l_r[r];
      ctx[((size_t)b * 1024 + qr) * 1024 + h * 64 + g * 16 + lr] = f2bf(val);
    }
}

extern "C" void kernel_launch(void* const* d_in, const int* in_sizes, int n_in,
                              void* d_out, int out_size, void* d_ws, size_t ws_size,
                              hipStream_t stream) {
  const float* x     = (const float*)d_in[0];
  const float* mask  = (const float*)d_in[2];
  const float* wq    = (const float*)d_in[3];
  const float* wk    = (const float*)d_in[4];
  const float* wv    = (const float*)d_in[5];
  const float* wo    = (const float*)d_in[6];
  const float* gamma = (const float*)d_in[7];
  const float* beta  = (const float*)d_in[8];
  float* out = (float*)d_out;

  char* ws = (char*)d_ws;
  u16* normed = (u16*)(ws);                       // 8 MiB
  u16* wcat   = (u16*)(ws + (8ull << 20));        // 8 MiB ([wq;wk;wv;wo])
  u16* Qg     = (u16*)(ws + (16ull << 20));       // 8 MiB
  u16* Kg     = (u16*)(ws + (24ull << 20));       // 8 MiB
  u16* Vtg    = (u16*)(ws + (32ull << 20));       // 8 MiB
  u16* ctx    = (u16*)(ws + (40ull << 20));       // 8 MiB
  u16* wo_bf  = wcat + 3072ull * 1024;

  ln_kernel<<<4096, 256, 0, stream>>>(x, gamma, beta, normed);
  cvt_w<<<4096, 256, 0, stream>>>(wq, wk, wv, wo, wcat);
  // QKV: M=4096, N=3072
  gemm_bt<0><<<dim3(24, 32), 256, 0, stream>>>(normed, wcat, Qg, Kg, Vtg, nullptr, nullptr);
  // attention: grid x=h (16 heads share per-b mask slice in L2), y=qtile, z=b
  flash_kernel<<<dim3(16, 16, 4), 256, 0, stream>>>(Qg, Kg, Vtg, mask, ctx);
  // WO + residual: M=4096, N=1024
  gemm_bt<1><<<dim3(8, 32), 256, 0, stream>>>(ctx, wo_bf, nullptr, nullptr, nullptr, out, x);
}

// Round 3
// 254.410 us; speedup vs baseline: 1.0842x; 1.0615x over previous
//
#include <hip/hip_runtime.h>
#include <hip/hip_bf16.h>

// Fused self-attention block: LN -> QKV -> MHA(16 heads, dh=64) -> WO -> +x
// B=4, S=1024, HIDDEN=1024. All inputs fp32; big GEMMs run bf16 MFMA w/ fp32 accum.
//
// R3 changes vs R2 (flash was latency-bound: MfmaUtil 8%, VALU 42%, HBM 13%):
//  - SWAPPED QK^T: mfma(K,Q) puts a full 64-key score row per lane (q=lane&15)
//    -> softmax reduce = in-register tree + 2 shfl_xor (was 32 shfl chain).
//  - bias precompute (cvt_bias): -10000*(1-mask) in bf16, fragment-ordered;
//    2 vector loads/thread/tile (was 16 scalar global loads).
//  - double-buffered K/V staging with raw s_barrier + asm vmcnt(0): next tile's
//    global_load_lds issued before current tile's compute (latency hidden).
//
// Workspace layout (48 MiB total):
//   [ 0,  8M)  normed   bf16 [4096][1024]   -> REUSED as bias after gemm0
//   [ 8, 16M)  wcat     bf16 [wq;wk;wv;wo] = [4096][1024]
//   [16, 24M)  Qg       bf16 [B,H,S,64]  (pre-scaled by 1/sqrt(64))
//   [24, 32M)  Kg       bf16 [B,H,S,64]
//   [32, 40M)  Vt       bf16 [B,H,64,S]
//   [40, 48M)  ctx      bf16 [4096][1024]  ([B,S,H,dh] flattened)

typedef unsigned short u16;
typedef __attribute__((ext_vector_type(8))) short short8;
typedef __attribute__((ext_vector_type(4))) float f32x4;

__device__ __forceinline__ u16 f2bf(float f) {
  union { float f; unsigned u; } cv; cv.f = f;
  unsigned u = cv.u + 0x7fffu + ((cv.u >> 16) & 1u);   // RNE
  return (u16)(u >> 16);
}

__device__ __forceinline__ float bf2f(u16 u) {
  union { unsigned u; float f; } cv; cv.u = ((unsigned)u) << 16;
  return cv.f;
}

__device__ __forceinline__ void gload_lds16(const void* g, void* l) {
  __builtin_amdgcn_global_load_lds(
      (const __attribute__((address_space(1))) void*)g,
      (__attribute__((address_space(3))) void*)l, 16, 0, 0);
}

__device__ __forceinline__ f32x4 mfma16(short8 a, short8 b, f32x4 c) {
  return __builtin_amdgcn_mfma_f32_16x16x32_bf16(a, b, c, 0, 0, 0);
}

// ---------------- LayerNorm: fp32 in -> bf16 normed ----------------
__global__ __launch_bounds__(256) void ln_kernel(const float* __restrict__ x,
                                                 const float* __restrict__ gamma,
                                                 const float* __restrict__ beta,
                                                 u16* __restrict__ outn) {
  __shared__ float sm[4];
  const int row = blockIdx.x, t = threadIdx.x;
  float4 v = ((const float4*)(x + (size_t)row * 1024))[t];
  float s = v.x + v.y + v.z + v.w;
#pragma unroll
  for (int off = 32; off; off >>= 1) s += __shfl_down(s, off);
  if ((t & 63) == 0) sm[t >> 6] = s;
  __syncthreads();
  const float mu = (sm[0] + sm[1] + sm[2] + sm[3]) * (1.0f / 1024.0f);
  const float dx = v.x - mu, dy = v.y - mu, dz = v.z - mu, dw = v.w - mu;
  float vs = dx * dx + dy * dy + dz * dz + dw * dw;
  __syncthreads();
#pragma unroll
  for (int off = 32; off; off >>= 1) vs += __shfl_down(vs, off);
  if ((t & 63) == 0) sm[t >> 6] = vs;
  __syncthreads();
  const float var = (sm[0] + sm[1] + sm[2] + sm[3]) * (1.0f / 1024.0f);
  const float rstd = rsqrtf(var + 1e-5f);
  float4 g = ((const float4*)gamma)[t];
  float4 b = ((const float4*)beta)[t];
  uint2 pk;
  pk.x = (unsigned)f2bf(dx * rstd * g.x + b.x) | ((unsigned)f2bf(dy * rstd * g.y + b.y) << 16);
  pk.y = (unsigned)f2bf(dz * rstd * g.z + b.z) | ((unsigned)f2bf(dw * rstd * g.w + b.w) << 16);
  *(uint2*)&outn[(size_t)row * 1024 + t * 4] = pk;
}

// ---------------- weight convert fp32 -> bf16, concat [wq;wk;wv;wo] ----------------
__global__ __launch_bounds__(256) void cvt_w(const float* __restrict__ wq,
                                             const float* __restrict__ wk,
                                             const float* __restrict__ wv,
                                             const float* __restrict__ wo,
                                             u16* __restrict__ out) {
  const int i = blockIdx.x * 256 + threadIdx.x;  // 1M threads, 4 elems each
  const int e = i * 4;
  const int seg = e >> 20;
  const int off = e & 1048575;
  const float* src = (seg == 0) ? wq : (seg == 1) ? wk : (seg == 2) ? wv : wo;
  float4 v = *(const float4*)(src + off);
  uint2 pk;
  pk.x = (unsigned)f2bf(v.x) | ((unsigned)f2bf(v.y) << 16);
  pk.y = (unsigned)f2bf(v.z) | ((unsigned)f2bf(v.w) << 16);
  *(uint2*)&out[e] = pk;
}

// ---------------- bias precompute: -10000*(1-mask) fp32 -> bf16, fragment order ----
// Layout: bias[b][q][kt][lg][16], the 16 = (kn 0..3)x(r 0..3) as two 8-groups
// (kn{0,1} then kn{2,3}). Flash lane (q=qbase+lr, lg) reads 32B per kt.
// Element (b,q,kt,lg,kn,r) corresponds to mask[b][q][kt*64 + kn*16 + lg*4 + r].
__global__ __launch_bounds__(256) void cvt_bias(const float* __restrict__ mask,
                                                u16* __restrict__ bias) {
  const int tid = blockIdx.x * 256 + threadIdx.x;  // 512K threads, 8 elems each
  const int half = tid & 1;
  const int lg = (tid >> 1) & 3;
  const int kt = (tid >> 3) & 15;
  const int q  = (tid >> 7) & 1023;
  const int b  = tid >> 17;
  const float* src = mask + ((size_t)b * 1024 + q) * 1024 + kt * 64 + lg * 4;
  float4 v0 = *(const float4*)(src + (half * 2 + 0) * 16);  // kn = half*2
  float4 v1 = *(const float4*)(src + (half * 2 + 1) * 16);  // kn = half*2+1
  uint4 w;
  w.x = (unsigned)f2bf(fmaf(10000.f, v0.x, -10000.f)) |
        ((unsigned)f2bf(fmaf(10000.f, v0.y, -10000.f)) << 16);
  w.y = (unsigned)f2bf(fmaf(10000.f, v0.z, -10000.f)) |
        ((unsigned)f2bf(fmaf(10000.f, v0.w, -10000.f)) << 16);
  w.z = (unsigned)f2bf(fmaf(10000.f, v1.x, -10000.f)) |
        ((unsigned)f2bf(fmaf(10000.f, v1.y, -10000.f)) << 16);
  w.w = (unsigned)f2bf(fmaf(10000.f, v1.z, -10000.f)) |
        ((unsigned)f2bf(fmaf(10000.f, v1.w, -10000.f)) << 16);
  *(uint4*)&bias[(size_t)tid * 8] = w;
}

// ---------------- bt-GEMM: C[M,N] = A[M,K] * Bt[N,K]^T  (K=1024) ----------------
// MODE 0: N=3072, scatter to Qg(*0.125)/Kg ([B,H,S,64]) and Vt ([B,H,64,S]) as bf16
// MODE 1: N=1024, fp32 out + residual
template <int MODE>
__global__ __launch_bounds__(256) void gemm_bt(const u16* __restrict__ A,
                                               const u16* __restrict__ Bm,
                                               u16* __restrict__ outQ, u16* __restrict__ outK,
                                               u16* __restrict__ outVt,
                                               float* __restrict__ outF,
                                               const float* __restrict__ resid) {
  constexpr int BK = 64, KK = 1024;
  __shared__ u16 As[128 * BK];
  __shared__ u16 Bs[128 * BK];
  const int m0 = blockIdx.y * 128, n0 = blockIdx.x * 128;
  const int t = threadIdx.x;
  const int wid = t >> 6, lane = t & 63;
  const int wm = (wid >> 1) * 64, wn = (wid & 1) * 64;
  const int lr = lane & 15, lg = lane >> 4;
  f32x4 acc[4][4] = {};
  const u16* aSrc = A + (size_t)(m0 + (t >> 3)) * KK + (t & 7) * 8;
  const u16* bSrc = Bm + (size_t)(n0 + (t >> 3)) * KK + (t & 7) * 8;

  for (int k0 = 0; k0 < KK; k0 += BK) {
    __syncthreads();
#pragma unroll
    for (int c = 0; c < 4; c++) {
      gload_lds16(aSrc + (size_t)c * 32 * KK + k0, As + c * 2048 + t * 8);
      gload_lds16(bSrc + (size_t)c * 32 * KK + k0, Bs + c * 2048 + t * 8);
    }
    __syncthreads();
    short8 af[4][2], bfr[4][2];
#pragma unroll
    for (int mi = 0; mi < 4; mi++)
#pragma unroll
      for (int kc = 0; kc < 2; kc++)
        af[mi][kc] = *(const short8*)&As[(wm + mi * 16 + lr) * BK + kc * 32 + lg * 8];
#pragma unroll
    for (int ni = 0; ni < 4; ni++)
#pragma unroll
      for (int kc = 0; kc < 2; kc++)
        bfr[ni][kc] = *(const short8*)&Bs[(wn + ni * 16 + lr) * BK + kc * 32 + lg * 8];
#pragma unroll
    for (int mi = 0; mi < 4; mi++)
#pragma unroll
      for (int ni = 0; ni < 4; ni++)
#pragma unroll
        for (int kc = 0; kc < 2; kc++)
          acc[mi][ni] = mfma16(af[mi][kc], bfr[ni][kc], acc[mi][ni]);
  }

#pragma unroll
  for (int mi = 0; mi < 4; mi++)
#pragma unroll
    for (int ni = 0; ni < 4; ni++)
#pragma unroll
      for (int r = 0; r < 4; r++) {
        const int i = m0 + wm + mi * 16 + lg * 4 + r;  // C row = (lane>>4)*4+reg
        const int j = n0 + wn + ni * 16 + lr;          // C col = lane&15
        const float val = acc[mi][ni][r];
        if (MODE == 0) {
          const int seg = j >> 10, jj = j & 1023;
          const int h = jj >> 6, d = jj & 63;
          const int b = i >> 10, s_ = i & 1023;
          if (seg == 0)      outQ[((size_t)(b * 16 + h) * 1024 + s_) * 64 + d] = f2bf(val * 0.125f);
          else if (seg == 1) outK[((size_t)(b * 16 + h) * 1024 + s_) * 64 + d] = f2bf(val);
          else               outVt[((size_t)(b * 16 + h) * 64 + d) * 1024 + s_] = f2bf(val);
        } else {
          const size_t o = (size_t)i * 1024 + j;
          outF[o] = val + resid[o];
        }
      }
}

// ---------------- flash attention: per (b,h,qtile=64) block, 4 waves x 16 q-rows ----
// SWAPPED QK^T: s = mfma(K, Q) -> C rows = keys (lg*4+r per 16-block), cols = q (lr).
// Each lane owns the full 64-key score row of q = qbase+lr (16 in-reg + 4 lg-groups).
// K/V LDS chunk-XOR swizzled as R2 (conflict-free). P goes through a per-wave
// 8B-chunk swizzled LDS buffer to become the PV A-operand.
__global__ __launch_bounds__(256) void flash_kernel(const u16* __restrict__ Qg,
                                                    const u16* __restrict__ Kg,
                                                    const u16* __restrict__ Vt,
                                                    const u16* __restrict__ bias,
                                                    u16* __restrict__ ctx) {
  const int h = blockIdx.x, qt = blockIdx.y, b = blockIdx.z;
  const int bh = b * 16 + h;
  __shared__ u16 Ks[2][4096];       // dbuf swizzled [key][d]
  __shared__ u16 Vs[2][4096];       // dbuf swizzled [d][key]
  __shared__ u16 Ps[4][1024];       // per-wave swizzled P [16 q][64 key]
  const int t = threadIdx.x, wid = t >> 6, lane = t & 63;
  const int lr = lane & 15, lg = lane >> 4;
  const int hR = lr & 7;
  const int qbase = qt * 64 + wid * 16;

  // Q fragments (B-operand): lane holds Q[q=qbase+lr][d-chunk lg*8..]; pre-scaled.
  short8 qf0, qf1;
  {
    const u16* qrow = Qg + ((size_t)bh * 1024 + qbase + lr) * 64;
    qf0 = *(const short8*)(qrow + lg * 8);
    qf1 = *(const short8*)(qrow + 32 + lg * 8);
  }
  f32x4 octx[4] = {};
  float m_ln = -1e30f, l_ln = 0.0f;  // online softmax state for q = qbase+lr

  const u16* kS0 = Kg + (size_t)bh * 65536;
  const u16* vS0 = Vt + (size_t)bh * 65536;
  const int srow = t >> 3, scb = t & 7;

  // bias: [b][q][kt][lg][16]; per-lane base for q=qbase+lr
  const u16* bptr = bias + ((size_t)b * 1024 + qbase + lr) * 1024 + lg * 16;

  auto STAGE = [&](int nb, int kt) {
#pragma unroll
    for (int c = 0; c < 2; c++) {
      const int row = c * 32 + srow;
      const int sc = (scb ^ (row & 7)) * 8;   // pre-swizzled source chunk
      gload_lds16(kS0 + (size_t)(kt * 64 + row) * 64 + sc, &Ks[nb][c * 2048 + t * 8]);
      gload_lds16(vS0 + (size_t)row * 1024 + kt * 64 + sc, &Vs[nb][c * 2048 + t * 8]);
    }
  };

  // prologue: stage tile 0, load its bias
  STAGE(0, 0);
  short8 bc0 = *(const short8*)(bptr);
  short8 bc1 = *(const short8*)(bptr + 8);
  asm volatile("s_waitcnt vmcnt(0)" ::: "memory");
  __builtin_amdgcn_s_barrier();
  __builtin_amdgcn_sched_barrier(0);

  int cur = 0;
  for (int kt = 0; kt < 16; kt++) {
    // issue next tile's staging + bias loads early (latency hides under compute)
    const int ktn = (kt < 15) ? kt + 1 : 15;
    STAGE(cur ^ 1, ktn);
    short8 bn0 = *(const short8*)(bptr + ktn * 64);
    short8 bn1 = *(const short8*)(bptr + ktn * 64 + 8);

    // ---- S = K Q^T: rows = keys, cols = q. sv[kn][r] = score(key kn*16+lg*4+r, q=lr)
    float sv[4][4];
#pragma unroll
    for (int kn = 0; kn < 4; kn++) {
      const int R = kn * 16 + lr;
      short8 kf0 = *(const short8*)&Ks[cur][R * 64 + ((lg ^ hR) << 3)];
      short8 kf1 = *(const short8*)&Ks[cur][R * 64 + (((lg + 4) ^ hR) << 3)];
      f32x4 s = {};
      s = mfma16(kf0, qf0, s);
      s = mfma16(kf1, qf1, s);
      short8 bsel = (kn < 2) ? bc0 : bc1;
#pragma unroll
      for (int r = 0; r < 4; r++)
        sv[kn][r] = s[r] + bf2f((u16)bsel[(kn & 1) * 4 + r]);
    }

    // ---- online softmax for q=lr: in-register tree + 2 shfl_xor
    float mx0 = fmaxf(fmaxf(sv[0][0], sv[0][1]), fmaxf(sv[0][2], sv[0][3]));
    float mx1 = fmaxf(fmaxf(sv[1][0], sv[1][1]), fmaxf(sv[1][2], sv[1][3]));
    float mx2 = fmaxf(fmaxf(sv[2][0], sv[2][1]), fmaxf(sv[2][2], sv[2][3]));
    float mx3 = fmaxf(fmaxf(sv[3][0], sv[3][1]), fmaxf(sv[3][2], sv[3][3]));
    float mt = fmaxf(fmaxf(mx0, mx1), fmaxf(mx2, mx3));
    mt = fmaxf(mt, __shfl_xor(mt, 16));
    mt = fmaxf(mt, __shfl_xor(mt, 32));
    const float mn = fmaxf(m_ln, mt);
    const float f = __expf(m_ln - mn);
    m_ln = mn;
    float ps = 0.0f;
#pragma unroll
    for (int kn = 0; kn < 4; kn++) {
      float p0 = __expf(sv[kn][0] - mn), p1 = __expf(sv[kn][1] - mn);
      float p2 = __expf(sv[kn][2] - mn), p3 = __expf(sv[kn][3] - mn);
      sv[kn][0] = p0; sv[kn][1] = p1; sv[kn][2] = p2; sv[kn][3] = p3;
      ps += (p0 + p1) + (p2 + p3);
    }
    ps += __shfl_xor(ps, 16);
    ps += __shfl_xor(ps, 32);
    l_ln = l_ln * f + ps;

    // rescale octx: factor for q-row lg*4+r lives at lane (own lg, lr'=lg*4+r)
    float fb[4];
#pragma unroll
    for (int r = 0; r < 4; r++)
      fb[r] = __shfl(f, (lane & 48) | (lg * 4 + r), 64);
#pragma unroll
    for (int g = 0; g < 4; g++)
#pragma unroll
      for (int r = 0; r < 4; r++) octx[g][r] *= fb[r];

    // ---- P -> per-wave swizzled LDS (chunk c=kn*4+lg holds keys 4c..4c+3)
    const int swz = (lr & 7) << 1;
#pragma unroll
    for (int kn = 0; kn < 4; kn++) {
      uint2 w;
      w.x = (unsigned)f2bf(sv[kn][0]) | ((unsigned)f2bf(sv[kn][1]) << 16);
      w.y = (unsigned)f2bf(sv[kn][2]) | ((unsigned)f2bf(sv[kn][3]) << 16);
      *(uint2*)&Ps[wid][lr * 64 + (((kn * 4 + lg) ^ swz) << 2)] = w;
    }
    // A-frags: lane reads P[q=lr][keys lg*8..+7] and [32+lg*8..+7]
    short8 pa0 = *(const short8*)&Ps[wid][lr * 64 + (((2 * lg) ^ swz) << 2)];
    short8 pa1 = *(const short8*)&Ps[wid][lr * 64 + (((8 + 2 * lg) ^ swz) << 2)];

    // ---- PV: A=P (rows=q), B=V (rows=d)
#pragma unroll
    for (int g = 0; g < 4; g++) {
      const int R = g * 16 + lr;
      short8 vf0 = *(const short8*)&Vs[cur][R * 64 + ((lg ^ hR) << 3)];
      short8 vf1 = *(const short8*)&Vs[cur][R * 64 + (((lg + 4) ^ hR) << 3)];
      octx[g] = mfma16(pa0, vf0, octx[g]);
      octx[g] = mfma16(pa1, vf1, octx[g]);
    }

    asm volatile("s_waitcnt vmcnt(0)" ::: "memory");
    __builtin_amdgcn_s_barrier();
    __builtin_amdgcn_sched_barrier(0);
    cur ^= 1;
    bc0 = bn0; bc1 = bn1;
  }

  // finalize: divide by l (broadcast like f), write ctx [B,S,H*dh] bf16
  float lb[4];
#pragma unroll
  for (int r = 0; r < 4; r++)
    lb[r] = __shfl(l_ln, (lane & 48) | (lg * 4 + r), 64);
#pragma unroll
  for (int g = 0; g < 4; g++)
#pragma unroll
    for (int r = 0; r < 4; r++) {
      const int qr = qbase + lg * 4 + r;
      ctx[((size_t)b * 1024 + qr) * 1024 + h * 64 + g * 16 + lr] = f2bf(octx[g][r] / lb[r]);
    }
}

extern "C" void kernel_launch(void* const* d_in, const int* in_sizes, int n_in,
                              void* d_out, int out_size, void* d_ws, size_t ws_size,
                              hipStream_t stream) {
  const float* x     = (const float*)d_in[0];
  const float* mask  = (const float*)d_in[2];
  const float* wq    = (const float*)d_in[3];
  const float* wk    = (const float*)d_in[4];
  const float* wv    = (const float*)d_in[5];
  const float* wo    = (const float*)d_in[6];
  const float* gamma = (const float*)d_in[7];
  const float* beta  = (const float*)d_in[8];
  float* out = (float*)d_out;

  char* ws = (char*)d_ws;
  u16* normed = (u16*)(ws);                       // 8 MiB (becomes bias after gemm0)
  u16* wcat   = (u16*)(ws + (8ull << 20));        // 8 MiB ([wq;wk;wv;wo])
  u16* Qg     = (u16*)(ws + (16ull << 20));       // 8 MiB
  u16* Kg     = (u16*)(ws + (24ull << 20));       // 8 MiB
  u16* Vtg    = (u16*)(ws + (32ull << 20));       // 8 MiB
  u16* ctx    = (u16*)(ws + (40ull << 20));       // 8 MiB
  u16* wo_bf  = wcat + 3072ull * 1024;
  u16* bias   = normed;                           // reuse after gemm0 consumed it

  ln_kernel<<<4096, 256, 0, stream>>>(x, gamma, beta, normed);
  cvt_w<<<4096, 256, 0, stream>>>(wq, wk, wv, wo, wcat);
  // QKV: M=4096, N=3072
  gemm_bt<0><<<dim3(24, 32), 256, 0, stream>>>(normed, wcat, Qg, Kg, Vtg, nullptr, nullptr);
  // bias precompute overwrites normed (dead after gemm0)
  cvt_bias<<<2048, 256, 0, stream>>>(mask, bias);
  // attention: grid x=h (16 heads share per-b bias slice in L2), y=qtile, z=b
  flash_kernel<<<dim3(16, 16, 4), 256, 0, stream>>>(Qg, Kg, Vtg, bias, ctx);
  // WO + residual: M=4096, N=1024
  gemm_bt<1><<<dim3(8, 32), 256, 0, stream>>>(ctx, wo_bf, nullptr, nullptr, nullptr, out, x);
}

// Round 4
// 223.274 us; speedup vs baseline: 1.2354x; 1.1395x over previous
//
#include <hip/hip_runtime.h>
#include <hip/hip_bf16.h>

// Fused self-attention block: LN -> QKV -> MHA(16 heads, dh=64) -> WO -> +x
// B=4, S=1024, HIDDEN=1024. All inputs fp32; big GEMMs run bf16 MFMA w/ fp32 accum.
//
// R4 changes vs R3 (gemm was LDS-conflict + staging-stall bound: MfmaUtil 14%,
// 9.4M bank conflicts, 2 barriers/iter):
//  - gemm: BK=32 double-buffered, stage-next -> compute -> one vmcnt(0)+s_barrier
//    per iter (flash-R3-proven sync pattern); XOR chunk swizzle on LDS (source-
//    side for global_load_lds + read-side) -> fragment reads 2-way max.
//  - gemm MODE0 epilogue: LDS-packed 16B stores for Q/K; V transposed in-epilogue
//    through swizzled per-wave LDS tile (was 64 scalar 2B scatter stores/thread).
//  - gemm MODE1: 64x128 tiles -> 512 wg (was 256).
//  - cvt_bias kernel DELETED: flash reads fp32 mask directly (float4-vectorizable
//    in swapped-QK layout), prefetched one tile ahead.
//
// Workspace layout (48 MiB total):
//   [ 0,  8M)  normed   bf16 [4096][1024]
//   [ 8, 16M)  wcat     bf16 [wq;wk;wv;wo] = [4096][1024]
//   [16, 24M)  Qg       bf16 [B,H,S,64]  (pre-scaled by 1/sqrt(64))
//   [24, 32M)  Kg       bf16 [B,H,S,64]
//   [32, 40M)  Vt       bf16 [B,H,64,S]
//   [40, 48M)  ctx      bf16 [4096][1024]  ([B,S,H,dh] flattened)

typedef unsigned short u16;
typedef __attribute__((ext_vector_type(8))) short short8;
typedef __attribute__((ext_vector_type(4))) float f32x4;

__device__ __forceinline__ u16 f2bf(float f) {
  union { float f; unsigned u; } cv; cv.f = f;
  unsigned u = cv.u + 0x7fffu + ((cv.u >> 16) & 1u);   // RNE
  return (u16)(u >> 16);
}

__device__ __forceinline__ void gload_lds16(const void* g, void* l) {
  __builtin_amdgcn_global_load_lds(
      (const __attribute__((address_space(1))) void*)g,
      (__attribute__((address_space(3))) void*)l, 16, 0, 0);
}

__device__ __forceinline__ f32x4 mfma16(short8 a, short8 b, f32x4 c) {
  return __builtin_amdgcn_mfma_f32_16x16x32_bf16(a, b, c, 0, 0, 0);
}

// ---------------- LayerNorm: fp32 in -> bf16 normed ----------------
__global__ __launch_bounds__(256) void ln_kernel(const float* __restrict__ x,
                                                 const float* __restrict__ gamma,
                                                 const float* __restrict__ beta,
                                                 u16* __restrict__ outn) {
  __shared__ float sm[4];
  const int row = blockIdx.x, t = threadIdx.x;
  float4 v = ((const float4*)(x + (size_t)row * 1024))[t];
  float s = v.x + v.y + v.z + v.w;
#pragma unroll
  for (int off = 32; off; off >>= 1) s += __shfl_down(s, off);
  if ((t & 63) == 0) sm[t >> 6] = s;
  __syncthreads();
  const float mu = (sm[0] + sm[1] + sm[2] + sm[3]) * (1.0f / 1024.0f);
  const float dx = v.x - mu, dy = v.y - mu, dz = v.z - mu, dw = v.w - mu;
  float vs = dx * dx + dy * dy + dz * dz + dw * dw;
  __syncthreads();
#pragma unroll
  for (int off = 32; off; off >>= 1) vs += __shfl_down(vs, off);
  if ((t & 63) == 0) sm[t >> 6] = vs;
  __syncthreads();
  const float var = (sm[0] + sm[1] + sm[2] + sm[3]) * (1.0f / 1024.0f);
  const float rstd = rsqrtf(var + 1e-5f);
  float4 g = ((const float4*)gamma)[t];
  float4 b = ((const float4*)beta)[t];
  uint2 pk;
  pk.x = (unsigned)f2bf(dx * rstd * g.x + b.x) | ((unsigned)f2bf(dy * rstd * g.y + b.y) << 16);
  pk.y = (unsigned)f2bf(dz * rstd * g.z + b.z) | ((unsigned)f2bf(dw * rstd * g.w + b.w) << 16);
  *(uint2*)&outn[(size_t)row * 1024 + t * 4] = pk;
}

// ---------------- weight convert fp32 -> bf16, concat [wq;wk;wv;wo] ----------------
__global__ __launch_bounds__(256) void cvt_w(const float* __restrict__ wq,
                                             const float* __restrict__ wk,
                                             const float* __restrict__ wv,
                                             const float* __restrict__ wo,
                                             u16* __restrict__ out) {
  const int i = blockIdx.x * 256 + threadIdx.x;  // 1M threads, 4 elems each
  const int e = i * 4;
  const int seg = e >> 20;
  const int off = e & 1048575;
  const float* src = (seg == 0) ? wq : (seg == 1) ? wk : (seg == 2) ? wv : wo;
  float4 v = *(const float4*)(src + off);
  uint2 pk;
  pk.x = (unsigned)f2bf(v.x) | ((unsigned)f2bf(v.y) << 16);
  pk.y = (unsigned)f2bf(v.z) | ((unsigned)f2bf(v.w) << 16);
  *(uint2*)&out[e] = pk;
}

// ---------------- bt-GEMM: C[M,N] = A[M,K] * Bt[N,K]^T  (K=1024) ----------------
// BK=32, double-buffered LDS, one barrier per K-step, XOR-swizzled tiles.
// MODE 0: BM=128, N=3072; epilogue via LDS -> packed 16B stores to
//         Qg(*0.125)/Kg [B,H,S,64] and transposed Vt [B,H,64,S].
// MODE 1: BM=64, N=1024; fp32 out + residual (direct stores).
template <int MODE>
__global__ __launch_bounds__(256) void gemm_bt(const u16* __restrict__ A,
                                               const u16* __restrict__ Bm,
                                               u16* __restrict__ outQ, u16* __restrict__ outK,
                                               u16* __restrict__ outVt,
                                               float* __restrict__ outF,
                                               const float* __restrict__ resid) {
  constexpr int BM = (MODE == 0) ? 128 : 64;
  constexpr int MI = BM / 32;                 // m-fragments per wave
  constexpr int ASZ = BM * 32;                // u16 per A buffer
  constexpr int BSZ = 128 * 32;               // u16 per B buffer
  constexpr int STG = 2 * ASZ + 2 * BSZ;      // staging u16
  constexpr int SMEM = (MODE == 0) ? (STG > 18432 ? STG : 18432) : STG;
  __shared__ u16 sm[SMEM];

  const int m0 = blockIdx.y * BM, n0 = blockIdx.x * 128;
  const int t = threadIdx.x;
  const int wid = t >> 6, lane = t & 63;
  const int wm = (wid >> 1) * (BM / 2), wn = (wid & 1) * 64;
  const int lr = lane & 15, lg = lane >> 4;
  const int swz = (lg ^ ((lr >> 1) & 3)) << 3;   // read-side chunk swizzle (u16 units)
  f32x4 acc[MI][4] = {};

  // staging: thread t owns LDS 16B chunk (row = cc*64 + t>>2, c = t&3);
  // source pre-swizzled: global col chunk = c ^ ((row>>1)&3) = (t&3)^((t>>3)&3)
  const int scol = (((t & 3) ^ ((t >> 3) & 3)) << 3);
  const u16* aT = A + (size_t)(m0 + (t >> 2)) * 1024 + scol;
  const u16* bT = Bm + (size_t)(n0 + (t >> 2)) * 1024 + scol;

  auto STAGE = [&](int buf, int kt) {
    const int k0 = kt * 32;
#pragma unroll
    for (int cc = 0; cc < BM / 64; cc++)
      gload_lds16(aT + (size_t)cc * 65536 + k0, &sm[buf * ASZ + cc * 2048 + t * 8]);
#pragma unroll
    for (int cc = 0; cc < 2; cc++)
      gload_lds16(bT + (size_t)cc * 65536 + k0, &sm[2 * ASZ + buf * BSZ + cc * 2048 + t * 8]);
  };

  STAGE(0, 0);
  asm volatile("s_waitcnt vmcnt(0)" ::: "memory");
  __builtin_amdgcn_s_barrier();
  __builtin_amdgcn_sched_barrier(0);

  int cur = 0;
  for (int kt = 0; kt < 32; kt++) {
    STAGE(cur ^ 1, (kt + 1) & 31);   // wrap: last iter restages tile 0 (never read)

    short8 af[MI], bfr[4];
#pragma unroll
    for (int mi = 0; mi < MI; mi++)
      af[mi] = *(const short8*)&sm[cur * ASZ + (wm + mi * 16 + lr) * 32 + swz];
#pragma unroll
    for (int ni = 0; ni < 4; ni++)
      bfr[ni] = *(const short8*)&sm[2 * ASZ + cur * BSZ + (wn + ni * 16 + lr) * 32 + swz];
    __builtin_amdgcn_s_setprio(1);
#pragma unroll
    for (int mi = 0; mi < MI; mi++)
#pragma unroll
      for (int ni = 0; ni < 4; ni++)
        acc[mi][ni] = mfma16(af[mi], bfr[ni], acc[mi][ni]);
    __builtin_amdgcn_s_setprio(0);

    asm volatile("s_waitcnt vmcnt(0)" ::: "memory");
    __builtin_amdgcn_s_barrier();
    __builtin_amdgcn_sched_barrier(0);
    cur ^= 1;
  }

  if (MODE == 1) {
    // direct fp32 + residual
#pragma unroll
    for (int mi = 0; mi < MI; mi++)
#pragma unroll
      for (int ni = 0; ni < 4; ni++)
#pragma unroll
        for (int r = 0; r < 4; r++) {
          const int i = m0 + wm + mi * 16 + lg * 4 + r;
          const int j = n0 + wn + ni * 16 + lr;
          const size_t o = (size_t)i * 1024 + j;
          outF[o] = acc[mi][ni][r] + resid[o];
        }
    return;
  }

  // ---- MODE 0 epilogue: per-wave LDS re-layout -> packed stores ----
  const int seg = (n0 + wn) >> 10;             // block/wave-uniform (tiles don't straddle)
  const int g8 = lane >> 3, j8 = lane & 7;     // packed-store lane roles
  if (seg < 2) {
    // Q/K: row-major pad-72 per-wave tile
    u16* epi = &sm[wid * 4608];
    const float qs = (seg == 0) ? 0.125f : 1.0f;
#pragma unroll
    for (int mi = 0; mi < 4; mi++)
#pragma unroll
      for (int ni = 0; ni < 4; ni++)
#pragma unroll
        for (int r = 0; r < 4; r++)
          epi[(mi * 16 + lg * 4 + r) * 72 + ni * 16 + lr] = f2bf(acc[mi][ni][r] * qs);
    __syncthreads();
    u16* dst = (seg == 0) ? outQ : outK;
    const int h = ((n0 + wn) & 1023) >> 6;
#pragma unroll
    for (int it = 0; it < 8; it++) {
      const int ml = it * 8 + g8;
      short8 v = *(const short8*)&epi[ml * 72 + j8 * 8];
      const int i = m0 + wm + ml;
      const int b = i >> 10, s_ = i & 1023;
      *(short8*)&dst[((size_t)(b * 16 + h) * 1024 + s_) * 64 + j8 * 8] = v;
    }
  } else {
    // V: transposed [n(d)][m(s)] XOR-swizzled per-wave tile (b64 granules)
    u16* epi = &sm[wid * 4096];
#pragma unroll
    for (int mi = 0; mi < 4; mi++)
#pragma unroll
      for (int ni = 0; ni < 4; ni++) {
        const int n = ni * 16 + lr;
        const int c2 = 4 * mi + lg;            // m-chunk of 4
        uint2 w;
        w.x = (unsigned)f2bf(acc[mi][ni][0]) | ((unsigned)f2bf(acc[mi][ni][1]) << 16);
        w.y = (unsigned)f2bf(acc[mi][ni][2]) | ((unsigned)f2bf(acc[mi][ni][3]) << 16);
        *(uint2*)&epi[n * 64 + ((c2 ^ (n & 15)) << 2)] = w;
      }
    __syncthreads();
    const int h = ((n0 + wn) & 1023) >> 6;
    const int b = (m0 + wm) >> 10, sb = (m0 + wm) & 1023;
#pragma unroll
    for (int it = 0; it < 8; it++) {
      const int n = it * 8 + g8;               // local d
      uint2 w0 = *(const uint2*)&epi[n * 64 + (((2 * j8) ^ (n & 15)) << 2)];
      uint2 w1 = *(const uint2*)&epi[n * 64 + (((2 * j8 + 1) ^ (n & 15)) << 2)];
      uint4 w; w.x = w0.x; w.y = w0.y; w.z = w1.x; w.w = w1.y;
      *(uint4*)&outVt[((size_t)(b * 16 + h) * 64 + n) * 1024 + sb + j8 * 8] = w;
    }
  }
}

// ---------------- flash attention: per (b,h,qtile=64) block, 4 waves x 16 q-rows ----
// SWAPPED QK^T: s = mfma(K, Q) -> rows = keys, cols = q (lane owns q = qbase+lr).
// K/V LDS chunk-XOR swizzled; dbuf with one vmcnt(0)+s_barrier per tile; mask
// read directly as float4 (fragment-aligned in swapped layout), prefetched.
__global__ __launch_bounds__(256) void flash_kernel(const u16* __restrict__ Qg,
                                                    const u16* __restrict__ Kg,
                                                    const u16* __restrict__ Vt,
                                                    const float* __restrict__ mask,
                                                    u16* __restrict__ ctx) {
  const int h = blockIdx.x, qt = blockIdx.y, b = blockIdx.z;
  const int bh = b * 16 + h;
  __shared__ u16 Ks[2][4096];       // dbuf swizzled [key][d]
  __shared__ u16 Vs[2][4096];       // dbuf swizzled [d][key]
  __shared__ u16 Ps[4][1024];       // per-wave swizzled P [16 q][64 key]
  const int t = threadIdx.x, wid = t >> 6, lane = t & 63;
  const int lr = lane & 15, lg = lane >> 4;
  const int hR = lr & 7;
  const int qbase = qt * 64 + wid * 16;

  short8 qf0, qf1;
  {
    const u16* qrow = Qg + ((size_t)bh * 1024 + qbase + lr) * 64;
    qf0 = *(const short8*)(qrow + lg * 8);
    qf1 = *(const short8*)(qrow + 32 + lg * 8);
  }
  f32x4 octx[4] = {};
  float m_ln = -1e30f, l_ln = 0.0f;

  const u16* kS0 = Kg + (size_t)bh * 65536;
  const u16* vS0 = Vt + (size_t)bh * 65536;
  const int srow = t >> 3, scb = t & 7;

  // mask row pointer for q = qbase+lr; per tile kt, lane reads
  // float4 at [kt*64 + kn*16 + lg*4] (keys kn*16+lg*4 .. +3)
  const float* mptr = mask + ((size_t)b * 1024 + qbase + lr) * 1024 + lg * 4;

  auto STAGE = [&](int nb, int kt) {
#pragma unroll
    for (int c = 0; c < 2; c++) {
      const int row = c * 32 + srow;
      const int sc = (scb ^ (row & 7)) * 8;
      gload_lds16(kS0 + (size_t)(kt * 64 + row) * 64 + sc, &Ks[nb][c * 2048 + t * 8]);
      gload_lds16(vS0 + (size_t)row * 1024 + kt * 64 + sc, &Vs[nb][c * 2048 + t * 8]);
    }
  };

  STAGE(0, 0);
  float mc[4][4];
#pragma unroll
  for (int kn = 0; kn < 4; kn++) {
    float4 v = *(const float4*)(mptr + kn * 16);
    mc[kn][0] = v.x; mc[kn][1] = v.y; mc[kn][2] = v.z; mc[kn][3] = v.w;
  }
  asm volatile("s_waitcnt vmcnt(0)" ::: "memory");
  __builtin_amdgcn_s_barrier();
  __builtin_amdgcn_sched_barrier(0);

  int cur = 0;
  for (int kt = 0; kt < 16; kt++) {
    const int ktn = (kt < 15) ? kt + 1 : 15;
    STAGE(cur ^ 1, ktn);
    float mnx[4][4];
#pragma unroll
    for (int kn = 0; kn < 4; kn++) {
      float4 v = *(const float4*)(mptr + ktn * 64 + kn * 16);
      mnx[kn][0] = v.x; mnx[kn][1] = v.y; mnx[kn][2] = v.z; mnx[kn][3] = v.w;
    }

    // ---- S = K Q^T: sv[kn][r] = score(key kn*16+lg*4+r, q=lr)
    float sv[4][4];
#pragma unroll
    for (int kn = 0; kn < 4; kn++) {
      const int R = kn * 16 + lr;
      short8 kf0 = *(const short8*)&Ks[cur][R * 64 + ((lg ^ hR) << 3)];
      short8 kf1 = *(const short8*)&Ks[cur][R * 64 + (((lg + 4) ^ hR) << 3)];
      f32x4 s = {};
      s = mfma16(kf0, qf0, s);
      s = mfma16(kf1, qf1, s);
      __builtin_amdgcn_s_setprio(0);
#pragma unroll
      for (int r = 0; r < 4; r++)
        sv[kn][r] = s[r] + fmaf(10000.f, mc[kn][r], -10000.f);
    }

    // ---- online softmax for q=lr: in-register tree + 2 shfl_xor
    float mx0 = fmaxf(fmaxf(sv[0][0], sv[0][1]), fmaxf(sv[0][2], sv[0][3]));
    float mx1 = fmaxf(fmaxf(sv[1][0], sv[1][1]), fmaxf(sv[1][2], sv[1][3]));
    float mx2 = fmaxf(fmaxf(sv[2][0], sv[2][1]), fmaxf(sv[2][2], sv[2][3]));
    float mx3 = fmaxf(fmaxf(sv[3][0], sv[3][1]), fmaxf(sv[3][2], sv[3][3]));
    float mt = fmaxf(fmaxf(mx0, mx1), fmaxf(mx2, mx3));
    mt = fmaxf(mt, __shfl_xor(mt, 16));
    mt = fmaxf(mt, __shfl_xor(mt, 32));
    const float mn = fmaxf(m_ln, mt);
    const float f = __expf(m_ln - mn);
    m_ln = mn;
    float ps = 0.0f;
#pragma unroll
    for (int kn = 0; kn < 4; kn++) {
      float p0 = __expf(sv[kn][0] - mn), p1 = __expf(sv[kn][1] - mn);
      float p2 = __expf(sv[kn][2] - mn), p3 = __expf(sv[kn][3] - mn);
      sv[kn][0] = p0; sv[kn][1] = p1; sv[kn][2] = p2; sv[kn][3] = p3;
      ps += (p0 + p1) + (p2 + p3);
    }
    ps += __shfl_xor(ps, 16);
    ps += __shfl_xor(ps, 32);
    l_ln = l_ln * f + ps;

    float fb[4];
#pragma unroll
    for (int r = 0; r < 4; r++)
      fb[r] = __shfl(f, (lane & 48) | (lg * 4 + r), 64);
#pragma unroll
    for (int g = 0; g < 4; g++)
#pragma unroll
      for (int r = 0; r < 4; r++) octx[g][r] *= fb[r];

    // ---- P -> per-wave swizzled LDS -> A-frags
    const int pswz = (lr & 7) << 1;
#pragma unroll
    for (int kn = 0; kn < 4; kn++) {
      uint2 w;
      w.x = (unsigned)f2bf(sv[kn][0]) | ((unsigned)f2bf(sv[kn][1]) << 16);
      w.y = (unsigned)f2bf(sv[kn][2]) | ((unsigned)f2bf(sv[kn][3]) << 16);
      *(uint2*)&Ps[wid][lr * 64 + (((kn * 4 + lg) ^ pswz) << 2)] = w;
    }
    short8 pa0 = *(const short8*)&Ps[wid][lr * 64 + (((2 * lg) ^ pswz) << 2)];
    short8 pa1 = *(const short8*)&Ps[wid][lr * 64 + (((8 + 2 * lg) ^ pswz) << 2)];

    // ---- PV
    __builtin_amdgcn_s_setprio(1);
#pragma unroll
    for (int g = 0; g < 4; g++) {
      const int R = g * 16 + lr;
      short8 vf0 = *(const short8*)&Vs[cur][R * 64 + ((lg ^ hR) << 3)];
      short8 vf1 = *(const short8*)&Vs[cur][R * 64 + (((lg + 4) ^ hR) << 3)];
      octx[g] = mfma16(pa0, vf0, octx[g]);
      octx[g] = mfma16(pa1, vf1, octx[g]);
    }
    __builtin_amdgcn_s_setprio(0);

    asm volatile("s_waitcnt vmcnt(0)" ::: "memory");
    __builtin_amdgcn_s_barrier();
    __builtin_amdgcn_sched_barrier(0);
    cur ^= 1;
#pragma unroll
    for (int kn = 0; kn < 4; kn++)
#pragma unroll
      for (int r = 0; r < 4; r++) mc[kn][r] = mnx[kn][r];
  }

  float lb[4];
#pragma unroll
  for (int r = 0; r < 4; r++)
    lb[r] = __shfl(l_ln, (lane & 48) | (lg * 4 + r), 64);
#pragma unroll
  for (int g = 0; g < 4; g++)
#pragma unroll
    for (int r = 0; r < 4; r++) {
      const int qr = qbase + lg * 4 + r;
      ctx[((size_t)b * 1024 + qr) * 1024 + h * 64 + g * 16 + lr] = f2bf(octx[g][r] / lb[r]);
    }
}

extern "C" void kernel_launch(void* const* d_in, const int* in_sizes, int n_in,
                              void* d_out, int out_size, void* d_ws, size_t ws_size,
                              hipStream_t stream) {
  const float* x     = (const float*)d_in[0];
  const float* mask  = (const float*)d_in[2];
  const float* wq    = (const float*)d_in[3];
  const float* wk    = (const float*)d_in[4];
  const float* wv    = (const float*)d_in[5];
  const float* wo    = (const float*)d_in[6];
  const float* gamma = (const float*)d_in[7];
  const float* beta  = (const float*)d_in[8];
  float* out = (float*)d_out;

  char* ws = (char*)d_ws;
  u16* normed = (u16*)(ws);                       // 8 MiB
  u16* wcat   = (u16*)(ws + (8ull << 20));        // 8 MiB ([wq;wk;wv;wo])
  u16* Qg     = (u16*)(ws + (16ull << 20));       // 8 MiB
  u16* Kg     = (u16*)(ws + (24ull << 20));       // 8 MiB
  u16* Vtg    = (u16*)(ws + (32ull << 20));       // 8 MiB
  u16* ctx    = (u16*)(ws + (40ull << 20));       // 8 MiB
  u16* wo_bf  = wcat + 3072ull * 1024;

  ln_kernel<<<4096, 256, 0, stream>>>(x, gamma, beta, normed);
  cvt_w<<<4096, 256, 0, stream>>>(wq, wk, wv, wo, wcat);
  // QKV: M=4096, N=3072, 128x128 tiles
  gemm_bt<0><<<dim3(24, 32), 256, 0, stream>>>(normed, wcat, Qg, Kg, Vtg, nullptr, nullptr);
  // attention: grid x=h (16 heads share per-b mask slice in L2), y=qtile, z=b
  flash_kernel<<<dim3(16, 16, 4), 256, 0, stream>>>(Qg, Kg, Vtg, mask, ctx);
  // WO + residual: M=4096, N=1024, 64x128 tiles
  gemm_bt<1><<<dim3(8, 64), 256, 0, stream>>>(ctx, wo_bf, nullptr, nullptr, nullptr, out, x);
}